// Round 2
// baseline (150.458 us; speedup 1.0000x reference)
//
#include <hip/hip_runtime.h>
#include <math.h>

#define S 128
#define NB 16
constexpr float STEP = 6.283185307179586f / 128.0f;   // 2*pi/128

// Kernel 1: F[b,y,s] = sum_v x[b,y,v] e^{-2pi i s v/S}, stored TRANSPOSED:
//   Ft[(b*S + s)*S + y]
// block = (b,y), 128 threads (thread index = s). All trig via a 128-entry
// LDS table built once per block (exact small angles, no accumulation drift).
__global__ void dft_rows(const float* __restrict__ in, float2* __restrict__ Ft) {
    const int by = blockIdx.x;
    const int b  = by >> 7;
    const int y  = by & (S - 1);
    const int s  = threadIdx.x;

    __shared__ float row[S];
    __shared__ float cosT[S], sinT[S];
    row[s] = in[((b * 2 + 0) * S + y) * S + s];
    float sn, cs;
    __sincosf((float)s * STEP, &sn, &cs);
    cosT[s] = cs;
    sinT[s] = sn;
    __syncthreads();

    float re = 0.f, im = 0.f;
#pragma unroll 8
    for (int v = 0; v < S; ++v) {
        const int k = (s * v) & (S - 1);
        const float xv = row[v];              // LDS broadcast
        re = fmaf(xv,  cosT[k], re);
        im = fmaf(xv, -sinT[k], im);
    }
    Ft[(b * S + s) * S + y] = make_float2(re, im);
}

// Kernel 2: blocks 0..2047: (b,s) tile — writes contiguous 64 KiB:
//   out[((b*129 + s)*S + y)*S + x] = (1/S)(Fre*cos(2pi s x/S) - Fim*sin(2pi s x/S))
// blocks 2048..2063: copy channel 1 of batch b to out channel 128.
__global__ void modulate(const float2* __restrict__ Ft, const float* __restrict__ in,
                         float* __restrict__ out) {
    const int blk = blockIdx.x;
    const int t   = threadIdx.x;              // 0..255

    if (blk >= NB * S) {                      // passthrough blocks (uniform branch)
        const int b = blk - NB * S;
        const float4* src = (const float4*)&in[((b * 2 + 1) * S) * S];
        float4*       dst = (float4*)&out[((b * 129 + S) * S) * S];
#pragma unroll
        for (int i = 0; i < 16; ++i)
            dst[i * 256 + t] = src[i * 256 + t];
        return;
    }

    const int b = blk >> 7;
    const int s = blk & (S - 1);

    __shared__ float2 Fs[S];                  // F[b, y, s] for all y
    __shared__ float  cosT[S], sinT[S];
    if (t < S) {
        Fs[t] = Ft[(b * S + s) * S + t];      // contiguous 1 KiB
        float sn, cs;
        __sincosf((float)t * STEP, &sn, &cs);
        cosT[t] = cs;
        sinT[t] = sn;
    }
    __syncthreads();

    const int x0 = (t & 31) * 4;              // this thread's 4 x values
    const int y0 = t >> 5;                    // 0..7, y advances by 8

    float mc[4], ms[4];                       // modulation factors, read once
#pragma unroll
    for (int j = 0; j < 4; ++j) {
        const int k = (s * (x0 + j)) & (S - 1);
        mc[j] = cosT[k];
        ms[j] = sinT[k];
    }

    float* obase = &out[((b * 129 + s) * S) * S];
#pragma unroll
    for (int i = 0; i < 16; ++i) {
        const int y = y0 + i * 8;
        const float2 f  = Fs[y];              // LDS broadcast per 32-lane group
        const float  re = f.x * (1.0f / S);
        const float  im = f.y * (1.0f / S);
        float4 o;
        o.x = re * mc[0] - im * ms[0];
        o.y = re * mc[1] - im * ms[1];
        o.z = re * mc[2] - im * ms[2];
        o.w = re * mc[3] - im * ms[3];
        *(float4*)&obase[y * S + x0] = o;     // wave writes 1 KiB contiguous
    }
}

extern "C" void kernel_launch(void* const* d_in, const int* in_sizes, int n_in,
                              void* d_out, int out_size, void* d_ws, size_t ws_size,
                              hipStream_t stream) {
    const float* in  = (const float*)d_in[0];
    float*       out = (float*)d_out;
    float2*      Ft  = (float2*)d_ws;         // 16*128*128 float2 = 2 MiB

    dft_rows<<<NB * S, S, 0, stream>>>(in, Ft);
    modulate<<<NB * S + NB, 256, 0, stream>>>(Ft, in, out);
}